// Round 12
// baseline (4360.526 us; speedup 1.0000x reference)
//
#include <hip/hip_runtime.h>

#define SEQ_T 512
#define BATCH_N 128
#define ISZ 256
#define HSZ 512
#define G4 2048                    // 4*HSZ
#define HSLOT (BATCH_N * HSZ * 2)  // 131072 bytes per bf16 h step-slot

typedef __attribute__((ext_vector_type(8))) short short8;
typedef __attribute__((ext_vector_type(4))) float f32x4;
typedef __attribute__((ext_vector_type(4))) unsigned int u32x4;

__device__ __forceinline__ unsigned short f2bf(float f) {
  unsigned u = __builtin_bit_cast(unsigned, f);
  u = u + 0x7FFFu + ((u >> 16) & 1u);
  return (unsigned short)(u >> 16);
}
__device__ __forceinline__ float sigm(float x) {
  x = fminf(fmaxf(x, -30.f), 30.f);
  return 1.f / (1.f + __expf(-x));
}
__device__ __forceinline__ float tanh_f(float x) {
  x = fminf(fmaxf(x, -15.f), 15.f);
  float e = __expf(2.f * x);
  return (e - 1.f) / (e + 1.f);
}

// ---- system-coherent (MALL) access primitives (HW-proven r1-r5, r9, r11) ----
__device__ __forceinline__ u32x4 ld_coh16(const void* p) {
  u32x4 v;
  asm volatile("global_load_dwordx4 %0, %1, off sc0 sc1" : "=v"(v) : "v"(p));
  return v;
}
__device__ __forceinline__ void st_coh4(void* p, unsigned v) {
  asm volatile("global_store_dword %0, %1, off sc0 sc1" : : "v"(p), "v"(v) : "memory");
}
__device__ __forceinline__ void wait_vm0() {
  asm volatile("s_waitcnt vmcnt(0)" ::: "memory");
  __builtin_amdgcn_sched_barrier(0);
}

// ---------------- prep: f32 -> bf16 weights + x, bias sum ----------------
__global__ void prep_kernel(const float* __restrict__ Wih_f, const float* __restrict__ Whh_f,
                            const float* __restrict__ bih, const float* __restrict__ bhh,
                            const float* __restrict__ x_f,
                            short* __restrict__ Wih_bf, short* __restrict__ Whh_bf,
                            float* __restrict__ bias, short* __restrict__ x_bf) {
  int stride = gridDim.x * blockDim.x;
  int i0 = blockIdx.x * blockDim.x + threadIdx.x;
  for (int i = i0; i < G4 * HSZ; i += stride) Whh_bf[i] = (short)f2bf(Whh_f[i]);
  for (int i = i0; i < G4 * ISZ; i += stride) Wih_bf[i] = (short)f2bf(Wih_f[i]);
  for (int i = i0; i < G4; i += stride) bias[i] = bih[i] + bhh[i];
  for (size_t i = i0; i < (size_t)BATCH_N * SEQ_T * ISZ; i += stride)
    x_bf[i] = (short)f2bf(x_f[i]);
}

// ---------------- fused persistent recurrence: no LDS, no barriers ----------------
// 128 wgs: grp = bid&7 (16 batches, XCD co-located under round-robin),
// jt = bid>>3 (32 hidden units). Wave w's lanes hold all 4 gates for their
// own (batch, j) pairs (gate-interleaved A rows, r11-proven) -> update fully
// in-register. h(t) is polled DIRECTLY into MFMA B-fragment registers:
// lane (hi,lo) owns h[batch=lo][k=ks*32+hi*8..+8] = 16 x 16B chunks; chunk
// ks <- producer wg ks, wave hi (1:1 for the lagged-flag fallback).
// r9-proven protocol: fresh zeroed slots, zero-poll retry, fire-forget pubs.
__global__ __launch_bounds__(256, 1) void rec_kernel(
    const short* __restrict__ xbf, const short* __restrict__ Wih,
    const short* __restrict__ Whh, const float* __restrict__ bias,
    char* __restrict__ hbufs, unsigned int* __restrict__ flags,
    float* __restrict__ hfin) {
  const int tid = threadIdx.x;
  const int bid = blockIdx.x;
  const int grp = bid & 7;
  const int jt = bid >> 3;
  const int w = tid >> 6, lane = tid & 63, lo = lane & 15, hi = lane >> 4;

  // ---- weight fragments, gate-interleaved rows (r11-proven mapping) ----
  // A-row lo -> (gate = lo&3, m = lo>>2); acc0[r] = gate r at
  // (batch=lo, j = jt*32 + w*8 + 2*hi); acc1[r] = same at j+1.
  short8 wh0[16], wh1[16], wx0[8], wx1[8];
  {
    const int arow = (lo & 3) * HSZ + jt * 32 + w * 8 + 2 * (lo >> 2);
    const short* b0 = Whh + (size_t)arow * HSZ + hi * 8;
    const short* b1 = b0 + HSZ;  // row+1 (odd j)
#pragma unroll
    for (int ks = 0; ks < 16; ++ks) {
      wh0[ks] = *(const short8*)(b0 + ks * 32);
      wh1[ks] = *(const short8*)(b1 + ks * 32);
    }
    const short* c0 = Wih + (size_t)arow * ISZ + hi * 8;
    const short* c1 = c0 + ISZ;
#pragma unroll
    for (int ks = 0; ks < 8; ++ks) {
      wx0[ks] = *(const short8*)(c0 + ks * 32);
      wx1[ks] = *(const short8*)(c1 + ks * 32);
    }
  }
  const int jev = jt * 32 + w * 8 + 2 * hi;  // this lane's even j
  float b4a[4], b4b[4];
#pragma unroll
  for (int r = 0; r < 4; ++r) {
    b4a[r] = bias[r * HSZ + jev];
    b4b[r] = bias[r * HSZ + jev + 1];
  }

  // ---- x fragments: lane loads x_bf[batch=grp*16+lo][t][k=ks*32+hi*8..+8] ----
  const short* xp = xbf + (size_t)(grp * 16 + lo) * SEQ_T * ISZ + hi * 8;
  short8 xf[8];
#pragma unroll
  for (int ks = 0; ks < 8; ++ks) xf[ks] = *(const short8*)(xp + ks * 32);  // x(0)

  // ---- h poll base for this lane ----
  const char* hb = hbufs + (size_t)(grp * 16 + lo) * 1024 + hi * 16;

  float cx = 0.f, cy = 0.f;

  for (int t = 0; t < SEQ_T; ++t) {
    // ---- acquire h(t) directly into B-fragment registers ----
    u32x4 hf[16];
    if (t > 0) {
      const char* rp = hb + (size_t)t * HSLOT;
      int spin = 0;
      for (;;) {
#pragma unroll
        for (int ks = 0; ks < 16; ++ks) hf[ks] = ld_coh16(rp + ks * 64);
        wait_vm0();  // also drains x(t) prefetch + own h(t) publishes
        unsigned mn = 0xFFFFFFFFu;
#pragma unroll
        for (int ks = 0; ks < 16; ++ks) {
          mn = hf[ks][0] < mn ? hf[ks][0] : mn;
          mn = hf[ks][1] < mn ? hf[ks][1] : mn;
          mn = hf[ks][2] < mn ? hf[ks][2] : mn;
          mn = hf[ks][3] < mn ? hf[ks][3] : mn;
        }
        if (mn != 0u) break;  // every dword nonzero => all producers landed
        if (++spin > 2048) {
          // fallback: legit-zero h words — confirm via producer flags, reload
          bool ok = true;
#pragma unroll
          for (int ks = 0; ks < 16; ++ks) {
            unsigned fv = __hip_atomic_load(&flags[((grp * 16 + ks) * 4 + hi) * 8],
                                            __ATOMIC_RELAXED, __HIP_MEMORY_SCOPE_AGENT);
            ok = ok && (fv >= (unsigned)t);
          }
          if (ok) {
#pragma unroll
            for (int ks = 0; ks < 16; ++ks) hf[ks] = ld_coh16(rp + ks * 64);
            wait_vm0();
            break;
          }
          spin = 0;
        }
      }
      // lagged flag: this wave's h(t) stores were drained by the poll waits
      if (lane == 0)
        __hip_atomic_store(&flags[((grp * 16 + jt) * 4 + w) * 8], (unsigned)t,
                           __ATOMIC_RELAXED, __HIP_MEMORY_SCOPE_AGENT);
    }

    // ---- gates = W_hh·h + W_ih·x + bias (K = 512 + 256), all registers ----
    f32x4 acc0 = {0.f, 0.f, 0.f, 0.f}, acc1 = {0.f, 0.f, 0.f, 0.f};
    if (t > 0) {
#pragma unroll
      for (int ks = 0; ks < 16; ++ks) {
        short8 bf = __builtin_bit_cast(short8, hf[ks]);
        acc0 = __builtin_amdgcn_mfma_f32_16x16x32_bf16(wh0[ks], bf, acc0, 0, 0, 0);
        acc1 = __builtin_amdgcn_mfma_f32_16x16x32_bf16(wh1[ks], bf, acc1, 0, 0, 0);
      }
    }
#pragma unroll
    for (int ks = 0; ks < 8; ++ks) {
      acc0 = __builtin_amdgcn_mfma_f32_16x16x32_bf16(wx0[ks], xf[ks], acc0, 0, 0, 0);
      acc1 = __builtin_amdgcn_mfma_f32_16x16x32_bf16(wx1[ks], xf[ks], acc1, 0, 0, 0);
    }

    // ---- prefetch x(t+1) fragments (plain cached; drained by next poll) ----
    if (t < SEQ_T - 1) {
      const short* xq = xp + (size_t)(t + 1) * ISZ;
#pragma unroll
      for (int ks = 0; ks < 8; ++ks) xf[ks] = *(const short8*)(xq + ks * 32);
    }

    // ---- in-register activations + c/h update ----
    {
      float i0 = sigm(acc0[0] + b4a[0]);
      float f0 = sigm(acc0[1] + b4a[1]);
      float g0 = tanh_f(acc0[2] + b4a[2]);
      float o0 = sigm(acc0[3] + b4a[3]);
      cx = f0 * cx + i0 * g0;
      float h0 = o0 * tanh_f(cx);
      float i1 = sigm(acc1[0] + b4b[0]);
      float f1 = sigm(acc1[1] + b4b[1]);
      float g1 = tanh_f(acc1[2] + b4b[2]);
      float o1 = sigm(acc1[3] + b4b[3]);
      cy = f1 * cy + i1 * g1;
      float h1 = o1 * tanh_f(cy);
      if (t < SEQ_T - 1) {
        // one 4B word per adjacent-j pair (word-atomic for the zero-poll)
        unsigned hp = (unsigned)f2bf(h0) | ((unsigned)f2bf(h1) << 16);
        char* dst = hbufs + (size_t)(t + 1) * HSLOT +
                    ((size_t)(grp * 16 + lo) * HSZ + jev) * 2;
        st_coh4(dst, hp);  // fire-and-forget
      } else {
        float2 hv;
        hv.x = h0;
        hv.y = h1;
        *(float2*)(hfin + (size_t)(grp * 16 + lo) * HSZ + jev) = hv;
      }
    }
  }
}

// ---------------- out = h_last @ W_lin^T + b_lin ----------------
__global__ void final_kernel(const float* __restrict__ hfin, const float* __restrict__ Wlin,
                             const float* __restrict__ blin, float* __restrict__ out) {
  int b = blockIdx.x;
  int l = threadIdx.x;  // 64 threads = 1 wave
  float s = 0.f;
#pragma unroll
  for (int k = 0; k < 8; ++k) s += hfin[(size_t)b * HSZ + k * 64 + l] * Wlin[k * 64 + l];
  for (int off = 32; off; off >>= 1) s += __shfl_down(s, off);
  if (l == 0) out[b] = s + blin[0];
}

extern "C" void kernel_launch(void* const* d_in, const int* in_sizes, int n_in,
                              void* d_out, int out_size, void* d_ws, size_t ws_size,
                              hipStream_t stream) {
  const float* x = (const float*)d_in[0];
  const float* Wih = (const float*)d_in[1];
  const float* Whh = (const float*)d_in[2];
  const float* bih = (const float*)d_in[3];
  const float* bhh = (const float*)d_in[4];
  const float* Wlin = (const float*)d_in[5];
  const float* blin = (const float*)d_in[6];
  float* out = (float*)d_out;

  char* ws = (char*)d_ws;
  size_t off = 0;
  auto alloc = [&](size_t sz) {
    char* p = ws + off;
    off += (sz + 255) & ~(size_t)255;
    return p;
  };
  unsigned* flags = (unsigned*)alloc(128 * 4 * 8 * 4);  // per (wg, wave), 32B apart
  char* hbufs = (char*)alloc((size_t)SEQ_T * HSLOT);    // 64MB fresh h slots
  size_t zero_bytes = off;  // flags + hbufs zeroed every launch (replay reset)
  float* hfin = (float*)alloc((size_t)BATCH_N * HSZ * 4);
  float* bias = (float*)alloc((size_t)G4 * 4);
  short* Wih_bf = (short*)alloc((size_t)G4 * ISZ * 2);
  short* Whh_bf = (short*)alloc((size_t)G4 * HSZ * 2);
  short* x_bf = (short*)alloc((size_t)BATCH_N * SEQ_T * ISZ * 2);  // 32MB
  (void)n_in; (void)in_sizes; (void)out_size; (void)ws_size;

  hipMemsetAsync(d_ws, 0, zero_bytes, stream);
  prep_kernel<<<2048, 256, 0, stream>>>(Wih, Whh, bih, bhh, x, Wih_bf, Whh_bf, bias, x_bf);
  rec_kernel<<<dim3(128), dim3(256), 0, stream>>>(x_bf, Wih_bf, Whh_bf, bias, hbufs, flags, hfin);
  final_kernel<<<dim3(BATCH_N), dim3(64), 0, stream>>>(hfin, Wlin, blin, out);
}

// Round 14
// 1772.926 us; speedup vs baseline: 2.4595x; 2.4595x over previous
//
#include <hip/hip_runtime.h>

#define SEQ_T 512
#define BATCH_N 128
#define ISZ 256
#define HSZ 512
#define G4 2048                    // 4*HSZ
#define HSLOT (BATCH_N * HSZ * 2)  // 131072 bytes per bf16 h step-slot

typedef __attribute__((ext_vector_type(8))) short short8;
typedef __attribute__((ext_vector_type(4))) float f32x4;
typedef __attribute__((ext_vector_type(4))) unsigned int u32x4;

__device__ __forceinline__ unsigned short f2bf(float f) {
  unsigned u = __builtin_bit_cast(unsigned, f);
  u = u + 0x7FFFu + ((u >> 16) & 1u);
  return (unsigned short)(u >> 16);
}
__device__ __forceinline__ float sigm(float x) {
  x = fminf(fmaxf(x, -30.f), 30.f);
  return 1.f / (1.f + __expf(-x));
}
__device__ __forceinline__ float tanh_f(float x) {
  x = fminf(fmaxf(x, -15.f), 15.f);
  float e = __expf(2.f * x);
  return (e - 1.f) / (e + 1.f);
}

// ---- system-coherent (MALL) access primitives (HW-proven r1-r5, r9, r11) ----
__device__ __forceinline__ u32x4 ld_coh16(const void* p) {
  u32x4 v;
  asm volatile("global_load_dwordx4 %0, %1, off sc0 sc1" : "=v"(v) : "v"(p));
  return v;
}
__device__ __forceinline__ void st_coh4(void* p, unsigned v) {
  asm volatile("global_store_dword %0, %1, off sc0 sc1" : : "v"(p), "v"(v) : "memory");
}
__device__ __forceinline__ void wait_vm0() {
  asm volatile("s_waitcnt vmcnt(0)" ::: "memory");
  __builtin_amdgcn_sched_barrier(0);
}
__device__ __forceinline__ bool anyz(u32x4 v) {
  return (v[0] == 0u) || (v[1] == 0u) || (v[2] == 0u) || (v[3] == 0u);
}

// ---------------- prep: f32 -> bf16 weights + x, bias sum ----------------
__global__ void prep_kernel(const float* __restrict__ Wih_f, const float* __restrict__ Whh_f,
                            const float* __restrict__ bih, const float* __restrict__ bhh,
                            const float* __restrict__ x_f,
                            short* __restrict__ Wih_bf, short* __restrict__ Whh_bf,
                            float* __restrict__ bias, short* __restrict__ x_bf) {
  int stride = gridDim.x * blockDim.x;
  int i0 = blockIdx.x * blockDim.x + threadIdx.x;
  for (int i = i0; i < G4 * HSZ; i += stride) Whh_bf[i] = (short)f2bf(Whh_f[i]);
  for (int i = i0; i < G4 * ISZ; i += stride) Wih_bf[i] = (short)f2bf(Wih_f[i]);
  for (int i = i0; i < G4; i += stride) bias[i] = bih[i] + bhh[i];
  for (size_t i = i0; i < (size_t)BATCH_N * SEQ_T * ISZ; i += stride)
    x_bf[i] = (short)f2bf(x_f[i]);
}

// ---------------- fused persistent recurrence (r11 + x-in-registers) ----------------
// 128 wgs: grp = bid&7 (16 batches, XCD co-located), jt = bid>>3 (32 j).
// Gate-interleaved A rows -> in-register c/h update, ONE barrier per step.
// h exchange byte-identical to r11 (r9-proven data-poll). x path now fully
// register-resident: per-lane B-fragments loaded as plain cached short8
// (r12-proven mapping), smemX deleted.
__global__ __launch_bounds__(256, 1) void rec_kernel(
    const short* __restrict__ xbf, const short* __restrict__ Wih,
    const short* __restrict__ Whh, const float* __restrict__ bias,
    char* __restrict__ hbufs, unsigned int* __restrict__ flags,
    float* __restrict__ hfin) {
  __shared__ char smemH[32768];   // 2 x [16][512] bf16, XOR-swizzled (parity t&1)

  const int tid = threadIdx.x;
  const int bid = blockIdx.x;
  const int grp = bid & 7;
  const int jt = bid >> 3;
  const int w = tid >> 6, lane = tid & 63, lo = lane & 15, hi = lane >> 4;
  const int ub = tid >> 4;   // batch_loc 0..15 (staging/poll role)
  const int seg = tid & 15;  // 32-j segment / producer index (staging/poll role)

  // ---- weight fragments, gate-interleaved rows (r11-proven mapping) ----
  // A-row lo -> (gate = lo&3, m = lo>>2); acc0[r] = gate r at
  // (batch=lo, j = jt*32 + w*8 + 2*hi); acc1[r] = same at j+1.
  short8 wh0[16], wh1[16], wx0[8], wx1[8];
  {
    const int arow = (lo & 3) * HSZ + jt * 32 + w * 8 + 2 * (lo >> 2);
    const short* b0 = Whh + (size_t)arow * HSZ + hi * 8;
    const short* b1 = b0 + HSZ;  // row+1 (odd j)
#pragma unroll
    for (int ks = 0; ks < 16; ++ks) {
      wh0[ks] = *(const short8*)(b0 + ks * 32);
      wh1[ks] = *(const short8*)(b1 + ks * 32);
    }
    const short* c0 = Wih + (size_t)arow * ISZ + hi * 8;
    const short* c1 = c0 + ISZ;
#pragma unroll
    for (int ks = 0; ks < 8; ++ks) {
      wx0[ks] = *(const short8*)(c0 + ks * 32);
      wx1[ks] = *(const short8*)(c1 + ks * 32);
    }
  }
  const int jev = jt * 32 + w * 8 + 2 * hi;  // this lane's even j
  float b4a[4], b4b[4];
#pragma unroll
  for (int r = 0; r < 4; ++r) {
    b4a[r] = bias[r * HSZ + jev];
    b4b[r] = bias[r * HSZ + jev + 1];
  }

  // ---- x fragments in registers (r12-proven mapping) ----
  // lane (hi,lo) B-frag: x[batch=grp*16+lo][t][k = ks*32 + hi*8 .. +8]
  const short* xp = xbf + (size_t)(grp * 16 + lo) * SEQ_T * ISZ + hi * 8;
  short8 xf[8];
#pragma unroll
  for (int ks = 0; ks < 8; ++ks) xf[ks] = *(const short8*)(xp + ks * 32);  // x(0)

  // zero h tile parity-0 for t=0
  for (int i = tid; i < 1024; i += 256) ((u32x4*)smemH)[i] = (u32x4){0u, 0u, 0u, 0u};

  float cx = 0.f, cy = 0.f;

  for (int t = 0; t < SEQ_T; ++t) {
    const int par = t & 1;
    // ---- acquire h(t): poll directly on data (r9/r11-proven) ----
    if (t > 0) {
      const char* rp = hbufs + (size_t)t * HSLOT +
                       ((size_t)(grp * 16 + ub) * HSZ + seg * 32) * 2;
      u32x4 v0, v1, v2, v3;
      int spin = 0;
      for (;;) {
        v0 = ld_coh16(rp);
        v1 = ld_coh16(rp + 16);
        v2 = ld_coh16(rp + 32);
        v3 = ld_coh16(rp + 48);
        wait_vm0();
        if (!(anyz(v0) || anyz(v1) || anyz(v2) || anyz(v3))) break;
        if (++spin > 2048) {
          // fallback: legit-zero h words — confirm via producer flag, reload
          if (__hip_atomic_load(&flags[(grp * 16 + seg) * 32], __ATOMIC_RELAXED,
                                __HIP_MEMORY_SCOPE_AGENT) >= (unsigned)t) {
            v0 = ld_coh16(rp);
            v1 = ld_coh16(rp + 16);
            v2 = ld_coh16(rp + 32);
            v3 = ld_coh16(rp + 48);
            wait_vm0();
            break;
          }
          spin = 0;
        }
      }
      int base = par * 16384 + ub * 1024 + seg * 64;
      int sw = (ub & 7) << 4;
      *(u32x4*)(smemH + (((base + 0) ^ sw))) = v0;
      *(u32x4*)(smemH + (((base + 16) ^ sw))) = v1;
      *(u32x4*)(smemH + (((base + 32) ^ sw))) = v2;
      *(u32x4*)(smemH + (((base + 48) ^ sw))) = v3;
    }
    __syncthreads();  // B_a — the step's only barrier
    // lagged flag: own h(t) stores were drained by this step's poll waits
    if (t > 0 && tid == 0)
      __hip_atomic_store(&flags[(grp * 16 + jt) * 32], (unsigned)t, __ATOMIC_RELAXED,
                         __HIP_MEMORY_SCOPE_AGENT);

    // ---- gates = W_hh·h + W_ih·x + bias (K = 512 + 256) ----
    f32x4 acc0 = {0.f, 0.f, 0.f, 0.f}, acc1 = {0.f, 0.f, 0.f, 0.f};
    const int hrow = par * 16384 + lo * 1024, hsw = (lo & 7) << 4;
#pragma unroll
    for (int ks = 0; ks < 16; ++ks) {
      short8 bf = *(const short8*)(smemH + ((hrow + ks * 64 + hi * 16) ^ hsw));
      acc0 = __builtin_amdgcn_mfma_f32_16x16x32_bf16(wh0[ks], bf, acc0, 0, 0, 0);
      acc1 = __builtin_amdgcn_mfma_f32_16x16x32_bf16(wh1[ks], bf, acc1, 0, 0, 0);
    }
#pragma unroll
    for (int ks = 0; ks < 8; ++ks) {
      acc0 = __builtin_amdgcn_mfma_f32_16x16x32_bf16(wx0[ks], xf[ks], acc0, 0, 0, 0);
      acc1 = __builtin_amdgcn_mfma_f32_16x16x32_bf16(wx1[ks], xf[ks], acc1, 0, 0, 0);
    }

    // ---- in-register activations + c/h update (no LDS, no extra barrier) ----
    {
      float i0 = sigm(acc0[0] + b4a[0]);
      float f0 = sigm(acc0[1] + b4a[1]);
      float g0 = tanh_f(acc0[2] + b4a[2]);
      float o0 = sigm(acc0[3] + b4a[3]);
      cx = f0 * cx + i0 * g0;
      float h0 = o0 * tanh_f(cx);
      float i1 = sigm(acc1[0] + b4b[0]);
      float f1 = sigm(acc1[1] + b4b[1]);
      float g1 = tanh_f(acc1[2] + b4b[2]);
      float o1 = sigm(acc1[3] + b4b[3]);
      cy = f1 * cy + i1 * g1;
      float h1 = o1 * tanh_f(cy);
      if (t < SEQ_T - 1) {
        // single 4B word per adjacent-j pair (word-atomic for the zero-poll)
        unsigned hp = (unsigned)f2bf(h0) | ((unsigned)f2bf(h1) << 16);
        char* dst = hbufs + (size_t)(t + 1) * HSLOT +
                    ((size_t)(grp * 16 + lo) * HSZ + jev) * 2;
        st_coh4(dst, hp);  // fire-and-forget; staggers out per-wave
      } else {
        float2 hv;
        hv.x = h0;
        hv.y = h1;
        *(float2*)(hfin + (size_t)(grp * 16 + lo) * HSZ + jev) = hv;
      }
    }

    // ---- prefetch x(t+1) fragments (plain cached; compiler-managed waits) ----
    if (t < SEQ_T - 1) {
      const short* xq = xp + (size_t)(t + 1) * ISZ;
#pragma unroll
      for (int ks = 0; ks < 8; ++ks) xf[ks] = *(const short8*)(xq + ks * 32);
    }
  }
}

// ---------------- out = h_last @ W_lin^T + b_lin ----------------
__global__ void final_kernel(const float* __restrict__ hfin, const float* __restrict__ Wlin,
                             const float* __restrict__ blin, float* __restrict__ out) {
  int b = blockIdx.x;
  int l = threadIdx.x;  // 64 threads = 1 wave
  float s = 0.f;
#pragma unroll
  for (int k = 0; k < 8; ++k) s += hfin[(size_t)b * HSZ + k * 64 + l] * Wlin[k * 64 + l];
  for (int off = 32; off; off >>= 1) s += __shfl_down(s, off);
  if (l == 0) out[b] = s + blin[0];
}

extern "C" void kernel_launch(void* const* d_in, const int* in_sizes, int n_in,
                              void* d_out, int out_size, void* d_ws, size_t ws_size,
                              hipStream_t stream) {
  const float* x = (const float*)d_in[0];
  const float* Wih = (const float*)d_in[1];
  const float* Whh = (const float*)d_in[2];
  const float* bih = (const float*)d_in[3];
  const float* bhh = (const float*)d_in[4];
  const float* Wlin = (const float*)d_in[5];
  const float* blin = (const float*)d_in[6];
  float* out = (float*)d_out;

  char* ws = (char*)d_ws;
  size_t off = 0;
  auto alloc = [&](size_t sz) {
    char* p = ws + off;
    off += (sz + 255) & ~(size_t)255;
    return p;
  };
  unsigned* flags = (unsigned*)alloc(128 * 32 * 4);   // 16KB, 128B/producer
  char* hbufs = (char*)alloc((size_t)SEQ_T * HSLOT);  // 64MB fresh h slots
  size_t zero_bytes = off;  // flags + hbufs zeroed every launch (replay reset)
  float* hfin = (float*)alloc((size_t)BATCH_N * HSZ * 4);
  float* bias = (float*)alloc((size_t)G4 * 4);
  short* Wih_bf = (short*)alloc((size_t)G4 * ISZ * 2);
  short* Whh_bf = (short*)alloc((size_t)G4 * HSZ * 2);
  short* x_bf = (short*)alloc((size_t)BATCH_N * SEQ_T * ISZ * 2);  // 32MB
  (void)n_in; (void)in_sizes; (void)out_size; (void)ws_size;

  hipMemsetAsync(d_ws, 0, zero_bytes, stream);
  prep_kernel<<<2048, 256, 0, stream>>>(Wih, Whh, bih, bhh, x, Wih_bf, Whh_bf, bias, x_bf);
  rec_kernel<<<dim3(128), dim3(256), 0, stream>>>(x_bf, Wih_bf, Whh_bf, bias, hbufs, flags, hfin);
  final_kernel<<<dim3(BATCH_N), dim3(64), 0, stream>>>(hfin, Wlin, blin, out);
}

// Round 15
// 1499.909 us; speedup vs baseline: 2.9072x; 1.1820x over previous
//
#include <hip/hip_runtime.h>

#define SEQ_T 512
#define BATCH_N 128
#define ISZ 256
#define HSZ 512
#define G4 2048                    // 4*HSZ
#define HSLOT (BATCH_N * HSZ * 2)  // 131072 bytes per bf16 h step-slot

typedef __attribute__((ext_vector_type(8))) short short8;
typedef __attribute__((ext_vector_type(4))) float f32x4;
typedef __attribute__((ext_vector_type(4))) unsigned int u32x4;

__device__ __forceinline__ unsigned short f2bf(float f) {
  unsigned u = __builtin_bit_cast(unsigned, f);
  u = u + 0x7FFFu + ((u >> 16) & 1u);
  return (unsigned short)(u >> 16);
}
__device__ __forceinline__ float sigm(float x) {
  x = fminf(fmaxf(x, -30.f), 30.f);
  return 1.f / (1.f + __expf(-x));
}
__device__ __forceinline__ float tanh_f(float x) {
  x = fminf(fmaxf(x, -15.f), 15.f);
  float e = __expf(2.f * x);
  return (e - 1.f) / (e + 1.f);
}

// ---- system-coherent (MALL) access primitives (HW-proven r1-r5, r9, r11) ----
__device__ __forceinline__ u32x4 ld_coh16(const void* p) {
  u32x4 v;
  asm volatile("global_load_dwordx4 %0, %1, off sc0 sc1" : "=v"(v) : "v"(p));
  return v;
}
__device__ __forceinline__ void st_coh4(void* p, unsigned v) {
  asm volatile("global_store_dword %0, %1, off sc0 sc1" : : "v"(p), "v"(v) : "memory");
}
__device__ __forceinline__ void wait_vm0() {
  asm volatile("s_waitcnt vmcnt(0)" ::: "memory");
  __builtin_amdgcn_sched_barrier(0);
}
__device__ __forceinline__ bool anyz(u32x4 v) {
  return (v[0] == 0u) || (v[1] == 0u) || (v[2] == 0u) || (v[3] == 0u);
}

// ---------------- prep: f32 -> bf16 weights, bias sum ----------------
__global__ void prep_kernel(const float* __restrict__ Wih_f, const float* __restrict__ Whh_f,
                            const float* __restrict__ bih, const float* __restrict__ bhh,
                            short* __restrict__ Wih_bf, short* __restrict__ Whh_bf,
                            float* __restrict__ bias) {
  int stride = gridDim.x * blockDim.x;
  int i0 = blockIdx.x * blockDim.x + threadIdx.x;
  for (int i = i0; i < G4 * HSZ; i += stride) Whh_bf[i] = (short)f2bf(Whh_f[i]);
  for (int i = i0; i < G4 * ISZ; i += stride) Wih_bf[i] = (short)f2bf(Wih_f[i]);
  for (int i = i0; i < G4; i += stride) bias[i] = bih[i] + bhh[i];
}

// ---------------- fused persistent recurrence (r11, validated 1510us) ----------------
// 128 wgs: grp = bid&7 (16 batches, XCD co-located under round-robin),
// jt = bid>>3 (32 hidden units). Gate-interleaved A rows -> each lane holds
// i,f,g,o for its own (batch, j) pair -> c/h update fully in-register, ONE
// barrier per step, publishes stagger out per-wave. smemH/smemX double-
// buffered (parity t&1). Exchange: r9-proven data-poll on fresh zeroed
// slots, fire-and-forget 4B publishes, lagged-flag fallback for legit zeros.
__global__ __launch_bounds__(256, 1) void rec_kernel(
    const float* __restrict__ x, const short* __restrict__ Wih,
    const short* __restrict__ Whh, const float* __restrict__ bias,
    char* __restrict__ hbufs, unsigned int* __restrict__ flags,
    float* __restrict__ hfin) {
  __shared__ char smemH[32768];   // 2 x [16][512] bf16, XOR-swizzled (parity t&1)
  __shared__ char smemX[16384];   // 2 x [16][256] bf16, XOR-swizzled (parity t&1)

  const int tid = threadIdx.x;
  const int bid = blockIdx.x;
  const int grp = bid & 7;
  const int jt = bid >> 3;
  const int w = tid >> 6, lane = tid & 63, lo = lane & 15, hi = lane >> 4;
  const int ub = tid >> 4;   // batch_loc 0..15 (staging/poll role)
  const int seg = tid & 15;  // 32-j segment / producer index (staging/poll role)

  // ---- weight fragments, gate-interleaved rows ----
  // A-row lo -> (gate = lo&3, m = lo>>2); W row = gate*HSZ + jt*32 + w*8 + 2m
  // block1 = +1 (odd j). C result: lane(hi,lo) acc0[r] = gate r at
  // (batch=lo, j = jt*32 + w*8 + 2*hi), acc1[r] = same at j+1.
  short8 wh0[16], wh1[16], wx0[8], wx1[8];
  {
    const int arow = (lo & 3) * HSZ + jt * 32 + w * 8 + 2 * (lo >> 2);
    const short* b0 = Whh + (size_t)arow * HSZ + hi * 8;
    const short* b1 = b0 + HSZ;  // row+1
#pragma unroll
    for (int ks = 0; ks < 16; ++ks) {
      wh0[ks] = *(const short8*)(b0 + ks * 32);
      wh1[ks] = *(const short8*)(b1 + ks * 32);
    }
    const short* c0 = Wih + (size_t)arow * ISZ + hi * 8;
    const short* c1 = c0 + ISZ;
#pragma unroll
    for (int ks = 0; ks < 8; ++ks) {
      wx0[ks] = *(const short8*)(c0 + ks * 32);
      wx1[ks] = *(const short8*)(c1 + ks * 32);
    }
  }
  const int jev = jt * 32 + w * 8 + 2 * hi;  // this lane's even j
  float b4a[4], b4b[4];
#pragma unroll
  for (int r = 0; r < 4; ++r) {
    b4a[r] = bias[r * HSZ + jev];
    b4b[r] = bias[r * HSZ + jev + 1];
  }

  // ---- x staging: this thread owns batch ub, elements seg*16..+15 ----
  const float* xrow = x + (size_t)(grp * 16 + ub) * SEQ_T * ISZ + seg * 16;
  const int xbase = ub * 512 + seg * 32;
  const int xsw = (ub & 7) << 4;
  {
    float4 a0 = *(const float4*)(xrow + 0);
    float4 a1 = *(const float4*)(xrow + 4);
    float4 a2 = *(const float4*)(xrow + 8);
    float4 a3 = *(const float4*)(xrow + 12);
    u32x4 p0, p1;
    p0[0] = f2bf(a0.x) | ((unsigned)f2bf(a0.y) << 16);
    p0[1] = f2bf(a0.z) | ((unsigned)f2bf(a0.w) << 16);
    p0[2] = f2bf(a1.x) | ((unsigned)f2bf(a1.y) << 16);
    p0[3] = f2bf(a1.z) | ((unsigned)f2bf(a1.w) << 16);
    p1[0] = f2bf(a2.x) | ((unsigned)f2bf(a2.y) << 16);
    p1[1] = f2bf(a2.z) | ((unsigned)f2bf(a2.w) << 16);
    p1[2] = f2bf(a3.x) | ((unsigned)f2bf(a3.y) << 16);
    p1[3] = f2bf(a3.z) | ((unsigned)f2bf(a3.w) << 16);
    *(u32x4*)(smemX + ((xbase + 0) ^ xsw)) = p0;   // parity-0 buffer
    *(u32x4*)(smemX + ((xbase + 16) ^ xsw)) = p1;
  }
  float4 xr0 = *(const float4*)(xrow + ISZ + 0);  // prefetch x(1)
  float4 xr1 = *(const float4*)(xrow + ISZ + 4);
  float4 xr2 = *(const float4*)(xrow + ISZ + 8);
  float4 xr3 = *(const float4*)(xrow + ISZ + 12);

  // zero h tile parity-0 for t=0
  for (int i = tid; i < 1024; i += 256) ((u32x4*)smemH)[i] = (u32x4){0u, 0u, 0u, 0u};

  float cx = 0.f, cy = 0.f;

  for (int t = 0; t < SEQ_T; ++t) {
    const int par = t & 1;
    // ---- acquire h(t): poll directly on data (r9-proven) ----
    if (t > 0) {
      const char* rp = hbufs + (size_t)t * HSLOT +
                       ((size_t)(grp * 16 + ub) * HSZ + seg * 32) * 2;
      u32x4 v0, v1, v2, v3;
      int spin = 0;
      for (;;) {
        v0 = ld_coh16(rp);
        v1 = ld_coh16(rp + 16);
        v2 = ld_coh16(rp + 32);
        v3 = ld_coh16(rp + 48);
        wait_vm0();
        if (!(anyz(v0) || anyz(v1) || anyz(v2) || anyz(v3))) break;
        if (++spin > 2048) {
          // fallback: legit-zero h words — confirm via producer flag, reload
          if (__hip_atomic_load(&flags[(grp * 16 + seg) * 32], __ATOMIC_RELAXED,
                                __HIP_MEMORY_SCOPE_AGENT) >= (unsigned)t) {
            v0 = ld_coh16(rp);
            v1 = ld_coh16(rp + 16);
            v2 = ld_coh16(rp + 32);
            v3 = ld_coh16(rp + 48);
            wait_vm0();
            break;
          }
          spin = 0;
        }
      }
      int base = par * 16384 + ub * 1024 + seg * 64;
      int sw = (ub & 7) << 4;
      *(u32x4*)(smemH + (((base + 0) ^ sw))) = v0;
      *(u32x4*)(smemH + (((base + 16) ^ sw))) = v1;
      *(u32x4*)(smemH + (((base + 32) ^ sw))) = v2;
      *(u32x4*)(smemH + (((base + 48) ^ sw))) = v3;
    }
    __syncthreads();  // B_a — the step's only barrier
    // lagged flag: own h(t) stores were drained by this step's poll waits
    if (t > 0 && tid == 0)
      __hip_atomic_store(&flags[(grp * 16 + jt) * 32], (unsigned)t, __ATOMIC_RELAXED,
                         __HIP_MEMORY_SCOPE_AGENT);

    // ---- gates = W_hh·h + W_ih·x + bias (K = 512 + 256) ----
    f32x4 acc0 = {0.f, 0.f, 0.f, 0.f}, acc1 = {0.f, 0.f, 0.f, 0.f};
    const int hrow = par * 16384 + lo * 1024, hsw = (lo & 7) << 4;
#pragma unroll
    for (int ks = 0; ks < 16; ++ks) {
      short8 bf = *(const short8*)(smemH + ((hrow + ks * 64 + hi * 16) ^ hsw));
      acc0 = __builtin_amdgcn_mfma_f32_16x16x32_bf16(wh0[ks], bf, acc0, 0, 0, 0);
      acc1 = __builtin_amdgcn_mfma_f32_16x16x32_bf16(wh1[ks], bf, acc1, 0, 0, 0);
    }
    const int xrowb = par * 8192 + lo * 512, xswr = (lo & 7) << 4;
#pragma unroll
    for (int ks = 0; ks < 8; ++ks) {
      short8 xf = *(const short8*)(smemX + ((xrowb + ks * 64 + hi * 16) ^ xswr));
      acc0 = __builtin_amdgcn_mfma_f32_16x16x32_bf16(wx0[ks], xf, acc0, 0, 0, 0);
      acc1 = __builtin_amdgcn_mfma_f32_16x16x32_bf16(wx1[ks], xf, acc1, 0, 0, 0);
    }

    // ---- in-register activations + c/h update (no LDS, no barrier) ----
    {
      float i0 = sigm(acc0[0] + b4a[0]);
      float f0 = sigm(acc0[1] + b4a[1]);
      float g0 = tanh_f(acc0[2] + b4a[2]);
      float o0 = sigm(acc0[3] + b4a[3]);
      cx = f0 * cx + i0 * g0;
      float h0 = o0 * tanh_f(cx);
      float i1 = sigm(acc1[0] + b4b[0]);
      float f1 = sigm(acc1[1] + b4b[1]);
      float g1 = tanh_f(acc1[2] + b4b[2]);
      float o1 = sigm(acc1[3] + b4b[3]);
      cy = f1 * cy + i1 * g1;
      float h1 = o1 * tanh_f(cy);
      if (t < SEQ_T - 1) {
        // single 4B word per adjacent-j pair (word-atomic for the zero-poll)
        unsigned hp = (unsigned)f2bf(h0) | ((unsigned)f2bf(h1) << 16);
        char* dst = hbufs + (size_t)(t + 1) * HSLOT +
                    ((size_t)(grp * 16 + lo) * HSZ + jev) * 2;
        st_coh4(dst, hp);  // fire-and-forget; staggers out per-wave
      } else {
        float2 hv;
        hv.x = h0;
        hv.y = h1;
        *(float2*)(hfin + (size_t)(grp * 16 + lo) * HSZ + jev) = hv;
      }
    }

    // ---- stage x(t+1) into parity (t+1)&1; prefetch x(t+2) ----
    if (t < SEQ_T - 1) {
      const int xb2 = ((t + 1) & 1) * 8192 + xbase;
      u32x4 p0, p1;
      p0[0] = f2bf(xr0.x) | ((unsigned)f2bf(xr0.y) << 16);
      p0[1] = f2bf(xr0.z) | ((unsigned)f2bf(xr0.w) << 16);
      p0[2] = f2bf(xr1.x) | ((unsigned)f2bf(xr1.y) << 16);
      p0[3] = f2bf(xr1.z) | ((unsigned)f2bf(xr1.w) << 16);
      p1[0] = f2bf(xr2.x) | ((unsigned)f2bf(xr2.y) << 16);
      p1[1] = f2bf(xr2.z) | ((unsigned)f2bf(xr2.w) << 16);
      p1[2] = f2bf(xr3.x) | ((unsigned)f2bf(xr3.y) << 16);
      p1[3] = f2bf(xr3.z) | ((unsigned)f2bf(xr3.w) << 16);
      *(u32x4*)(smemX + ((xb2 + 0) ^ xsw)) = p0;
      *(u32x4*)(smemX + ((xb2 + 16) ^ xsw)) = p1;
      if (t < SEQ_T - 2) {
        const float* xp = xrow + (size_t)(t + 2) * ISZ;
        xr0 = *(const float4*)(xp + 0);
        xr1 = *(const float4*)(xp + 4);
        xr2 = *(const float4*)(xp + 8);
        xr3 = *(const float4*)(xp + 12);
      }
    }
  }
}

// ---------------- out = h_last @ W_lin^T + b_lin ----------------
__global__ void final_kernel(const float* __restrict__ hfin, const float* __restrict__ Wlin,
                             const float* __restrict__ blin, float* __restrict__ out) {
  int b = blockIdx.x;
  int l = threadIdx.x;  // 64 threads = 1 wave
  float s = 0.f;
#pragma unroll
  for (int k = 0; k < 8; ++k) s += hfin[(size_t)b * HSZ + k * 64 + l] * Wlin[k * 64 + l];
  for (int off = 32; off; off >>= 1) s += __shfl_down(s, off);
  if (l == 0) out[b] = s + blin[0];
}

extern "C" void kernel_launch(void* const* d_in, const int* in_sizes, int n_in,
                              void* d_out, int out_size, void* d_ws, size_t ws_size,
                              hipStream_t stream) {
  const float* x = (const float*)d_in[0];
  const float* Wih = (const float*)d_in[1];
  const float* Whh = (const float*)d_in[2];
  const float* bih = (const float*)d_in[3];
  const float* bhh = (const float*)d_in[4];
  const float* Wlin = (const float*)d_in[5];
  const float* blin = (const float*)d_in[6];
  float* out = (float*)d_out;

  char* ws = (char*)d_ws;
  size_t off = 0;
  auto alloc = [&](size_t sz) {
    char* p = ws + off;
    off += (sz + 255) & ~(size_t)255;
    return p;
  };
  unsigned* flags = (unsigned*)alloc(128 * 32 * 4);   // 16KB, 128B/producer
  char* hbufs = (char*)alloc((size_t)SEQ_T * HSLOT);  // 64MB fresh h slots
  size_t zero_bytes = off;  // flags + hbufs zeroed every launch (replay reset)
  float* hfin = (float*)alloc((size_t)BATCH_N * HSZ * 4);
  float* bias = (float*)alloc((size_t)G4 * 4);
  short* Wih_bf = (short*)alloc((size_t)G4 * ISZ * 2);
  short* Whh_bf = (short*)alloc((size_t)G4 * HSZ * 2);
  (void)n_in; (void)in_sizes; (void)out_size; (void)ws_size;

  hipMemsetAsync(d_ws, 0, zero_bytes, stream);
  prep_kernel<<<1024, 256, 0, stream>>>(Wih, Whh, bih, bhh, Wih_bf, Whh_bf, bias);
  rec_kernel<<<dim3(128), dim3(256), 0, stream>>>(x, Wih_bf, Whh_bf, bias, hbufs, flags, hfin);
  final_kernel<<<dim3(BATCH_N), dim3(64), 0, stream>>>(hfin, Wlin, blin, out);
}